// Round 1
// baseline (1132.639 us; speedup 1.0000x reference)
//
#include <hip/hip_runtime.h>
#include <stdint.h>

typedef unsigned short u16;
typedef __bf16 bf16x8 __attribute__((ext_vector_type(8)));
typedef float f32x4 __attribute__((ext_vector_type(4)));

#define DEVI __device__ __forceinline__

static constexpr int DIM = 768;
static constexpr int SEQL = 3136;   // 56*56
static constexpr int MROWS = 25088; // 8*3136
static constexpr int HEADS = 12;
static constexpr int HD = 64;
static constexpr int NW = 196;      // tokens per window
static constexpr float QSCALE = 0.125f; // 64^-0.5
static constexpr int ATTN_SMEM = (208*64 + 208*64 + 64*224 + 4*16*224)*2 + 196*28*4; // 132544

DEVI float b2f(u16 u) { union { unsigned i; float f; } v; v.i = ((unsigned)u) << 16; return v.f; }
DEVI u16 f2b(float f) { union { float f; unsigned u; } v; v.f = f; return (u16)((v.u + 0x7FFFu + ((v.u >> 16) & 1u)) >> 16); }

DEVI void gl_lds16(const void* g, void* l) {
  __builtin_amdgcn_global_load_lds((const __attribute__((address_space(1))) void*)g,
                                   (__attribute__((address_space(3))) void*)l, 16, 0, 0);
}

// ---------------- weight transpose + f32->bf16 convert: W[K][N] -> Wt[N][K] ---------------
__global__ __launch_bounds__(256) void transpose_cvt(const float* __restrict__ in,
                                                     u16* __restrict__ out, int K, int N) {
  __shared__ float t[32][33];
  int n0 = blockIdx.x * 32, k0 = blockIdx.y * 32;
  int tx = threadIdx.x, ty = threadIdx.y; // (32,8)
  #pragma unroll
  for (int i = ty; i < 32; i += 8) t[i][tx] = in[(size_t)(k0 + i) * N + n0 + tx];
  __syncthreads();
  #pragma unroll
  for (int i = ty; i < 32; i += 8) out[(size_t)(n0 + i) * K + k0 + tx] = f2b(t[tx][i]);
}

// ---------------- layernorm (768 cols); REMAP=window-partition the output row ---------------
template<bool REMAP>
__global__ __launch_bounds__(256) void ln_kernel(const float* __restrict__ xin,
                                                 const float* __restrict__ g,
                                                 const float* __restrict__ bb,
                                                 u16* __restrict__ outw) {
  __shared__ float red[8];
  const int r = blockIdx.x;
  const int tid = threadIdx.x;
  const float* xr = xin + (size_t)r * DIM;
  float v0 = xr[tid], v1 = xr[tid + 256], v2 = xr[tid + 512];
  float s1 = v0 + v1 + v2;
  float s2 = v0 * v0 + v1 * v1 + v2 * v2;
  #pragma unroll
  for (int o = 32; o > 0; o >>= 1) { s1 += __shfl_down(s1, o); s2 += __shfl_down(s2, o); }
  const int l = tid & 63, w = tid >> 6;
  if (l == 0) { red[w] = s1; red[w + 4] = s2; }
  __syncthreads();
  float ts = red[0] + red[1] + red[2] + red[3];
  float tss = red[4] + red[5] + red[6] + red[7];
  float mean = ts * (1.f / 768.f);
  float var = tss * (1.f / 768.f) - mean * mean;
  float rstd = rsqrtf(var + 1e-5f);
  size_t orow;
  if constexpr (REMAP) {
    int b = r / SEQL, s = r % SEQL;
    int h = s / 56, ww = s % 56;
    orow = (size_t)(b * 16 + (h / 14) * 4 + (ww / 14)) * NW + (h % 14) * 14 + (ww % 14);
  } else {
    orow = (size_t)r;
  }
  u16* orp = outw + orow * DIM;
  orp[tid]       = f2b((v0 - mean) * rstd * g[tid]       + bb[tid]);
  orp[tid + 256] = f2b((v1 - mean) * rstd * g[tid + 256] + bb[tid + 256]);
  orp[tid + 512] = f2b((v2 - mean) * rstd * g[tid + 512] + bb[tid + 512]);
}

// ---------------- GEMM: A[M][K](bf16) x Bt[N][K](bf16) -> epilogue, 128x128x32 tiles ---------
struct Epi {
  const float* bias;
  const float* x;   // proj: residual input (f32)
  float* outf;      // proj/fc2: f32 out (d_out)
  u16* q; u16* k; u16* v; // qkv outputs
  u16* o16;         // fc1 out
};

template<int K, int N, int EPI>
__global__ __launch_bounds__(256)
void gemm_ep(const u16* __restrict__ A, const u16* __restrict__ Bt, Epi ep) {
  __shared__ __align__(16) u16 sA[128 * 32];
  __shared__ __align__(16) u16 sB[128 * 32];
  const int tid = threadIdx.x;
  const int l = tid & 63, w = tid >> 6;
  const int lr = l & 15, lg = l >> 4;
  const int nbn = N / 128;
  const int bm = blockIdx.x / nbn, bn = blockIdx.x % nbn;
  const int wm = (w >> 1) * 64, wn = (w & 1) * 64;

  const u16* Ab = A + (size_t)bm * 128 * K;
  const u16* Bb = Bt + (size_t)bn * 128 * K;

  f32x4 zero4 = {0.f, 0.f, 0.f, 0.f};
  f32x4 acc[4][4];
  #pragma unroll
  for (int i = 0; i < 4; ++i)
    #pragma unroll
    for (int j = 0; j < 4; ++j) acc[i][j] = zero4;

  const int so = w * 1024 + l * 16;      // lane byte offset in 4KB issue
  const int r0 = so >> 6;                // row (64B per row of 32 bf16)
  const int c0 = (so & 63) >> 1;         // col element

  for (int k0 = 0; k0 < K; k0 += 32) {
    __syncthreads();
    gl_lds16(Ab + (size_t)r0 * K + k0 + c0,        (char*)sA + (w * 1024));
    gl_lds16(Ab + (size_t)(r0 + 64) * K + k0 + c0, (char*)sA + (4096 + w * 1024));
    gl_lds16(Bb + (size_t)r0 * K + k0 + c0,        (char*)sB + (w * 1024));
    gl_lds16(Bb + (size_t)(r0 + 64) * K + k0 + c0, (char*)sB + (4096 + w * 1024));
    __syncthreads();
    bf16x8 af[4], bfv[4];
    #pragma unroll
    for (int mf = 0; mf < 4; ++mf)
      af[mf] = *(const bf16x8*)(sA + (wm + mf * 16 + lr) * 32 + lg * 8);
    #pragma unroll
    for (int nf = 0; nf < 4; ++nf)
      bfv[nf] = *(const bf16x8*)(sB + (wn + nf * 16 + lr) * 32 + lg * 8);
    #pragma unroll
    for (int mf = 0; mf < 4; ++mf)
      #pragma unroll
      for (int nf = 0; nf < 4; ++nf)
        acc[mf][nf] = __builtin_amdgcn_mfma_f32_16x16x32_bf16(af[mf], bfv[nf], acc[mf][nf], 0, 0, 0);
  }

  const int mrow0 = bm * 128 + wm + lg * 4;
  const int ncol0 = bn * 128 + wn + lr;
  #pragma unroll
  for (int mf = 0; mf < 4; ++mf) {
    #pragma unroll
    for (int nf = 0; nf < 4; ++nf) {
      #pragma unroll
      for (int e = 0; e < 4; ++e) {
        int r = mrow0 + mf * 16 + e;
        int c = ncol0 + nf * 16;
        float v = acc[mf][nf][e] + ep.bias[c];
        if constexpr (EPI == 0) { // qkv scatter
          int which = c / DIM;
          int hdc = c - which * DIM;
          int head = hdc >> 6, d = hdc & 63;
          int win = r / NW, pos = r - win * NW;
          size_t off = (((size_t)win * HEADS + head) * NW + pos) * HD + d;
          if (which == 0)      ep.q[off] = f2b(v * QSCALE);
          else if (which == 1) ep.k[off] = f2b(v);
          else                 ep.v[off] = f2b(v);
        } else if constexpr (EPI == 1) { // proj: window-reverse + residual -> f32 d_out
          int win = r / NW, pos = r - win * NW;
          int b = win >> 4, wi = win & 15;
          int hh = (wi >> 2) * 14 + pos / 14;
          int ww = (wi & 3) * 14 + pos % 14;
          size_t orow = (size_t)b * SEQL + hh * 56 + ww;
          ep.outf[orow * DIM + c] = ep.x[orow * DIM + c] + v;
        } else if constexpr (EPI == 2) { // fc1: exact GELU -> bf16
          float gg = 0.5f * v * (1.f + erff(v * 0.70710678118654752f));
          ep.o16[(size_t)r * N + c] = f2b(gg);
        } else { // fc2: residual with d_out (x1), write f32
          size_t idx = (size_t)r * N + c;
          ep.outf[idx] = ep.outf[idx] + v;
        }
      }
    }
  }
}

// ---------------- fused window attention: one block per (window, head) ---------------
__global__ __launch_bounds__(256)
void attn_kernel(const u16* __restrict__ qbuf, const u16* __restrict__ kbuf,
                 const u16* __restrict__ vbuf, const float* __restrict__ rph,
                 const float* __restrict__ rpw, u16* __restrict__ abuf) {
  extern __shared__ __align__(16) char smem[];
  u16* sQ = (u16*)smem;                   // [208][64]
  u16* sK = sQ + 208 * 64;                // [208][64]
  u16* sVt = sK + 208 * 64;               // [64][224]  (V transposed)
  u16* sP = sVt + 64 * 224;               // [4][16][224] per-wave P
  float* sRB = (float*)(sP + 4 * 16 * 224); // [196][28] rel bias (h then w)

  const int tid = threadIdx.x;
  const int wh = blockIdx.x;              // win*12 + head
  const int win = wh / HEADS, head = wh % HEADS;

  const uint4* Q4 = (const uint4*)(qbuf + (size_t)wh * NW * HD);
  const uint4* K4 = (const uint4*)(kbuf + (size_t)wh * NW * HD);
  const uint4* V4 = (const uint4*)(vbuf + (size_t)wh * NW * HD);
  uint4* sQ4 = (uint4*)sQ;
  uint4* sK4 = (uint4*)sK;
  uint4 z4; z4.x = z4.y = z4.z = z4.w = 0;
  for (int t = tid; t < 1568; t += 256) { sQ4[t] = Q4[t]; sK4[t] = K4[t]; }
  for (int t = tid; t < 96; t += 256) { sQ4[1568 + t] = z4; sK4[1568 + t] = z4; }
  for (int t = tid; t < 1568; t += 256) {
    uint4 vv = V4[t];
    const u16* pv = (const u16*)&vv;
    int pos = t >> 3, d0 = (t & 7) << 3;
    #pragma unroll
    for (int j = 0; j < 8; ++j) sVt[(d0 + j) * 224 + pos] = pv[j];
  }
  for (int t = tid; t < 64 * 28; t += 256) sVt[(t / 28) * 224 + 196 + (t % 28)] = 0;
  __syncthreads();

  // rel-pos bias table: sRB[i][jh] = q_i . rel_pos_h[ih-jh+13]; sRB[i][14+jw] = q_i . rel_pos_w[iw-jw+13]
  for (int idx = tid; idx < 196 * 28; idx += 256) {
    int i = idx / 28, t = idx % 28;
    int ih = i / 14, iw = i % 14;
    const float* rp = (t < 14) ? (rph + (size_t)(ih - t + 13) * HD)
                               : (rpw + (size_t)(iw - (t - 14) + 13) * HD);
    const uint4* qrow = (const uint4*)(sQ + i * HD);
    float a = 0.f;
    #pragma unroll
    for (int cb = 0; cb < 8; ++cb) {
      uint4 qv = qrow[cb];
      const u16* qs = (const u16*)&qv;
      #pragma unroll
      for (int j = 0; j < 8; ++j) a += b2f(qs[j]) * rp[cb * 8 + j];
    }
    sRB[idx] = a;
  }
  __syncthreads();

  const int l = tid & 63, w = tid >> 6;
  const int lr = l & 15, lg = l >> 4;
  u16* myP = sP + w * 16 * 224;

  int jq[13], jr[13];
  #pragma unroll
  for (int nf = 0; nf < 13; ++nf) {
    int j = nf * 16 + lr;
    jq[nf] = (j * 9363) >> 17;   // j/14 for j<224
    jr[nf] = j - jq[nf] * 14;
  }

  f32x4 zero4 = {0.f, 0.f, 0.f, 0.f};
  for (int chunk = w; chunk < 13; chunk += 4) {
    bf16x8 aq0 = *(const bf16x8*)(sQ + (chunk * 16 + lr) * HD + lg * 8);
    bf16x8 aq1 = *(const bf16x8*)(sQ + (chunk * 16 + lr) * HD + 32 + lg * 8);
    f32x4 accs[13];
    #pragma unroll
    for (int nf = 0; nf < 13; ++nf) {
      bf16x8 b0 = *(const bf16x8*)(sK + (nf * 16 + lr) * HD + lg * 8);
      bf16x8 b1 = *(const bf16x8*)(sK + (nf * 16 + lr) * HD + 32 + lg * 8);
      f32x4 c = zero4;
      c = __builtin_amdgcn_mfma_f32_16x16x32_bf16(aq0, b0, c, 0, 0, 0);
      c = __builtin_amdgcn_mfma_f32_16x16x32_bf16(aq1, b1, c, 0, 0, 0);
      accs[nf] = c;
    }
    const int i0 = chunk * 16 + lg * 4;
    float mrow[4] = {-3e38f, -3e38f, -3e38f, -3e38f};
    #pragma unroll
    for (int nf = 0; nf < 13; ++nf) {
      #pragma unroll
      for (int e = 0; e < 4; ++e) {
        int ic = i0 + e; if (ic > 195) ic = 195;
        float s = accs[nf][e] + sRB[ic * 28 + jq[nf]] + sRB[ic * 28 + 14 + jr[nf]];
        if (nf == 12 && lr >= 4) s = -1e30f;  // mask cols >= 196
        accs[nf][e] = s;
        mrow[e] = fmaxf(mrow[e], s);
      }
    }
    #pragma unroll
    for (int e = 0; e < 4; ++e) {
      float v = mrow[e];
      v = fmaxf(v, __shfl_xor(v, 1)); v = fmaxf(v, __shfl_xor(v, 2));
      v = fmaxf(v, __shfl_xor(v, 4)); v = fmaxf(v, __shfl_xor(v, 8));
      mrow[e] = v;
    }
    float ssum[4] = {0.f, 0.f, 0.f, 0.f};
    #pragma unroll
    for (int nf = 0; nf < 13; ++nf) {
      #pragma unroll
      for (int e = 0; e < 4; ++e) {
        float p = __expf(accs[nf][e] - mrow[e]);
        accs[nf][e] = p;
        ssum[e] += p;
      }
    }
    #pragma unroll
    for (int e = 0; e < 4; ++e) {
      float v = ssum[e];
      v += __shfl_xor(v, 1); v += __shfl_xor(v, 2);
      v += __shfl_xor(v, 4); v += __shfl_xor(v, 8);
      ssum[e] = 1.f / v;
    }
    #pragma unroll
    for (int nf = 0; nf < 13; ++nf)
      #pragma unroll
      for (int e = 0; e < 4; ++e)
        myP[(lg * 4 + e) * 224 + nf * 16 + lr] = f2b(accs[nf][e] * ssum[e]);
    #pragma unroll
    for (int e = 0; e < 4; ++e) myP[(lg * 4 + e) * 224 + 208 + lr] = 0;

    f32x4 acco[4];
    #pragma unroll
    for (int nf = 0; nf < 4; ++nf) acco[nf] = zero4;
    #pragma unroll
    for (int ks = 0; ks < 7; ++ks) {
      bf16x8 ap = *(const bf16x8*)(myP + lr * 224 + ks * 32 + lg * 8);
      #pragma unroll
      for (int nf = 0; nf < 4; ++nf) {
        bf16x8 bv = *(const bf16x8*)(sVt + (nf * 16 + lr) * 224 + ks * 32 + lg * 8);
        acco[nf] = __builtin_amdgcn_mfma_f32_16x16x32_bf16(ap, bv, acco[nf], 0, 0, 0);
      }
    }
    u16* ob = abuf + ((size_t)win * NW) * DIM + head * HD;
    #pragma unroll
    for (int nf = 0; nf < 4; ++nf)
      #pragma unroll
      for (int e = 0; e < 4; ++e) {
        int row = i0 + e;
        if (row < 196) ob[(size_t)row * DIM + nf * 16 + lr] = f2b(acco[nf][e]);
      }
  }
}

// ---------------- host launch ---------------
extern "C" void kernel_launch(void* const* d_in, const int* in_sizes, int n_in,
                              void* d_out, int out_size, void* d_ws, size_t ws_size,
                              hipStream_t stream) {
  (void)in_sizes; (void)n_in; (void)out_size; (void)ws_size;
  const float* x    = (const float*)d_in[0];
  const float* ln1s = (const float*)d_in[1];
  const float* ln1b = (const float*)d_in[2];
  const float* qkvw = (const float*)d_in[3];
  const float* qkvb = (const float*)d_in[4];
  const float* rph  = (const float*)d_in[5];
  const float* rpw  = (const float*)d_in[6];
  const float* pjw  = (const float*)d_in[7];
  const float* pjb  = (const float*)d_in[8];
  const float* ln2s = (const float*)d_in[9];
  const float* ln2b = (const float*)d_in[10];
  const float* f1w  = (const float*)d_in[11];
  const float* f1b  = (const float*)d_in[12];
  const float* f2w  = (const float*)d_in[13];
  const float* f2b_ = (const float*)d_in[14];
  float* out = (float*)d_out;

  // ws layout (bytes): [weightsT 14,155,776][xw/abuf/h1a 38,535,168][qkv/h1b 115,605,504][h2 38,535,168]
  char* ws = (char*)d_ws;
  u16* qkvwT = (u16*)ws;              // [2304][768]
  u16* projwT = qkvwT + 1769472;      // [768][768]
  u16* fc1wT  = qkvwT + 2359296;      // [3072][768]
  u16* fc2wT  = qkvwT + 4718592;      // [768][3072]
  u16* xw   = (u16*)(ws + 14155776);  // [25088][768]
  u16* qbuf = (u16*)(ws + 52690944);  // [1536][196][64]
  u16* kbuf = qbuf + 19267584;
  u16* vbuf = kbuf + 19267584;
  u16* h2   = (u16*)(ws + 168296448); // [25088][768]
  u16* abuf = xw;                     // alias (xw dead after qkv gemm)
  u16* h1   = xw;                     // [25088][3072] spans xw+qkv regions (both dead)

  (void)hipFuncSetAttribute((const void*)attn_kernel,
                            hipFuncAttributeMaxDynamicSharedMemorySize, ATTN_SMEM);

  dim3 tb(32, 8);
  transpose_cvt<<<dim3(2304 / 32, 768 / 32), tb, 0, stream>>>(qkvw, qkvwT, 768, 2304);
  transpose_cvt<<<dim3(768 / 32, 768 / 32),  tb, 0, stream>>>(pjw, projwT, 768, 768);
  transpose_cvt<<<dim3(3072 / 32, 768 / 32), tb, 0, stream>>>(f1w, fc1wT, 768, 3072);
  transpose_cvt<<<dim3(768 / 32, 3072 / 32), tb, 0, stream>>>(f2w, fc2wT, 3072, 768);

  ln_kernel<true><<<MROWS, 256, 0, stream>>>(x, ln1s, ln1b, xw);

  { Epi e{}; e.bias = qkvb; e.q = qbuf; e.k = kbuf; e.v = vbuf;
    gemm_ep<768, 2304, 0><<<196 * 18, 256, 0, stream>>>(xw, qkvwT, e); }

  attn_kernel<<<1536, 256, ATTN_SMEM, stream>>>(qbuf, kbuf, vbuf, rph, rpw, abuf);

  { Epi e{}; e.bias = pjb; e.x = x; e.outf = out;
    gemm_ep<768, 768, 1><<<196 * 6, 256, 0, stream>>>(abuf, projwT, e); }

  ln_kernel<false><<<MROWS, 256, 0, stream>>>(out, ln2s, ln2b, h2);

  { Epi e{}; e.bias = f1b; e.o16 = h1;
    gemm_ep<768, 3072, 2><<<196 * 24, 256, 0, stream>>>(h2, fc1wT, e); }

  { Epi e{}; e.bias = f2b_; e.outf = out;
    gemm_ep<3072, 768, 3><<<196 * 6, 256, 0, stream>>>(h1, fc2wT, e); }
}